// Round 6
// baseline (363.049 us; speedup 1.0000x reference)
//
#include <hip/hip_runtime.h>
#include <math.h>
#include <stdint.h>

// Problem: M=131072 rows, N=4000 verts (padded to 4096), D=16.
#define M_ROWS   131072
#define N_VERTS  4000
#define N_PAD    4096
#define D_DIM    16
#define N_TILES  (N_PAD / 32)          // 128 n-tiles of 32 verts
#define TILE_B   3072                  // per tile: yh 1KB | yl 1KB | ysf 1KB
#define CHUNK_T  4                     // tiles per LDS chunk (R6: 8->4 for 4 blocks/CU)
#define CHUNK_B  (CHUNK_T * TILE_B)    // 12288 B per chunk

// Scores are biased +128 so they are provably positive (score >= -||x||^2 and
// ||x||^2 < 128 for chi^2_16 data at astronomical confidence) -> positive-float
// bit pattern is monotone as u32 -> min_u32 does argmin via packed keys.
#define SCORE_BIAS 128.0f
// key = (score_bits & ~0xFF) | global_tile (0..127 fits 8 bits).
// Error budget: 8-bit mantissa truncation <= 7.8e-3 (score<256 for near-best),
// split-bf16 arithmetic ~1e-3, dropped al*yl cross term <= 4.9e-4,
// ys carried as bf16 hi+lo pair <= 7.3e-4.  TIE_EPS = 0.03 >= 2x total.
#define TIE_EPS 0.03f

#define WS_YFRAG_OFF 0
#define WS_PART_OFF  393216            // partials start here (launcher computes rest)

typedef float f32x16 __attribute__((ext_vector_type(16)));
typedef short s16x8  __attribute__((ext_vector_type(8)));

__device__ __forceinline__ unsigned short f32_to_bf16_rne(float f) {
    unsigned int u = __float_as_uint(f);
    u = (u + 0x7fffu + ((u >> 16) & 1u)) >> 16;
    return (unsigned short)u;
}
__device__ __forceinline__ float bf16_to_f32(unsigned short h) {
    return __uint_as_float(((unsigned int)h) << 16);
}
__device__ __forceinline__ uint32_t umin32(uint32_t a, uint32_t b) { return a < b ? a : b; }
__device__ __forceinline__ uint32_t umax32(uint32_t a, uint32_t b) { return a > b ? a : b; }

// median(a,b,c) in one VALU op. Under the invariant a <= c this equals
// min(c, max(a, b)) -- the second-best update. LLVM can't derive this
// (only valid under the invariant), so force v_med3_u32 via asm.
// Case check (b=new key kb): kb<a -> a; a<=kb<=c -> kb; kb>c -> c.  All match.
// Invariant preserved: min(a,kb) <= min(c, max(a,kb)).  [verified R4, absmax=0]
__device__ __forceinline__ uint32_t med3_u32(uint32_t a, uint32_t b, uint32_t c) {
    uint32_t d;
    asm("v_med3_u32 %0, %1, %2, %3" : "=v"(d) : "v"(a), "v"(b), "v"(c));
    return d;
}

// ---------------------------------------------------------------------------
// Kernel 1: pack Y into 32x32-MFMA fragment order.
// B-operand layout for mfma_f32_32x32x16_bf16 (verified R1/R2, absmax=0):
// B[n = lane&31][k = (lane>>5)*8 + j].
// Per tile T (32 verts): yh frag (64 lanes x 16B), yl frag, ysf frag.
// ysf holds (bias+||y||^2) as a bf16 hi/lo pair in k-slots 0,1 (lanes<32),
// consumed by an extra MFMA against a "ones" A-fragment -> acc init via MFMA.
// ---------------------------------------------------------------------------
__global__ void pack_y_kernel(const float* __restrict__ verts,
                              char* __restrict__ yfrag,
                              int* __restrict__ cnt) {
    const int tid = blockIdx.x * blockDim.x + threadIdx.x;   // 0..8191
    if (tid == 0) *cnt = 0;

    const int T   = tid >> 6;
    const int l   = tid & 63;
    const int col = l & 31;
    const int h   = l >> 5;
    const int n   = T * 32 + col;
    const int d0  = h * 8;

    float v[8];
    if (n < N_VERTS) {
        const float* y = verts + (size_t)n * D_DIM + d0;
#pragma unroll
        for (int j = 0; j < 8; ++j) v[j] = y[j];
    } else {
#pragma unroll
        for (int j = 0; j < 8; ++j) v[j] = 0.f;
    }
    s16x8 fh, fl;
#pragma unroll
    for (int j = 0; j < 8; ++j) {
        const unsigned short hh = f32_to_bf16_rne(v[j]);
        fh[j] = (short)hh;
        fl[j] = (short)f32_to_bf16_rne(v[j] - bf16_to_f32(hh));
    }
    char* tb = yfrag + (size_t)T * TILE_B + (size_t)l * 16;
    *(s16x8*)(tb)        = fh;
    *(s16x8*)(tb + 1024) = fl;

    // ysf: k-slots 0,1 (lanes < 32) hold bf16 hi/lo of bias+||y||^2.
    s16x8 fy;
#pragma unroll
    for (int j = 0; j < 8; ++j) fy[j] = 0;
    if (h == 0) {
        float ys;
        if (n < N_VERTS) {
            ys = SCORE_BIAS;
            const float* y = verts + (size_t)n * D_DIM;
#pragma unroll
            for (int d = 0; d < D_DIM; ++d) ys = fmaf(y[d], y[d], ys);
        } else {
            ys = 1e30f;   // pad cols never win
        }
        const unsigned short ysh = f32_to_bf16_rne(ys);
        fy[0] = (short)ysh;
        fy[1] = (short)f32_to_bf16_rne(ys - bf16_to_f32(ysh));
    }
    *(s16x8*)(tb + 2048) = fy;
}

// ---------------------------------------------------------------------------
// Kernel 2 (MFMA screen, 32x32x16, SPLIT-K over tiles): 512 thr = 8 waves,
// wave = 32 rows x (N_TILES >> lsplit) tiles. Block (mb, half): half =
// bid & (nsplit-1), mb = bid >> lsplit. Total waves doubles at lsplit=1 ->
// 8 waves/SIMD (R4-R5 post-mortem: kernel is stall-bound on the per-tile
// serial chain ds_read -> 4 chained MFMA -> key VALU; intra-wave ILP-2
// REGRESSED (R5, serial best[] RAW); TLP is the lever, and waves were
// grid-capped at 4/SIMD by the wave<->row binding).
// Per tile: acc = ah*yh + al*yh + ah*yl + ones*ysf (4 chained MFMAs).
// Key = (bits & ~0xFF) | global_tile -> min_u32 best, v_med3_u32 second.
// Emits per-row PARTIALS (bestKey, n, secondKey); merge_kernel combines.
// NOTE R3 post-mortem: global_load_lds DMA staging FAILED correctness
// (absmax 0.97) -- do not retry without an isolated A/B. Reg staging here.
// `#pragma unroll 1`: full unroll pipelines tiles -> spill (R1).
// __launch_bounds__(512,8): force VGPR<=64 so 8 waves/SIMD fit (pool 512/SIMD).
// Spill tripwire: FETCH_SIZE must stay ~<20 MB.
// ---------------------------------------------------------------------------
__global__ __launch_bounds__(512, 8) void mfma_screen_kernel(
    const float* __restrict__ x_all,    // (M,16)
    const char* __restrict__ yfrag,     // N_TILES x 3072 B
    uint32_t* __restrict__ pbk,         // [nsplit][M] best keys
    uint32_t* __restrict__ psk,         // [nsplit][M] second keys
    uint32_t* __restrict__ pn,          // [nsplit][M] best n
    int lsplit)                         // 0 or 1
{
    __shared__ __align__(16) char s_buf[32768];   // 2x12KB chunks; 32KB reduce

    const int bid  = blockIdx.x;
    const int half = bid & ((1 << lsplit) - 1);
    const int mb   = bid >> lsplit;
    const int tid  = threadIdx.x;
    const int wave = tid >> 6;
    const int lane = tid & 63;
    const int col  = lane & 31;          // A row / B col / C-D col
    const int h    = lane >> 5;          // k-half select
    const int rowBase = mb * 256 + wave * 32;

    const int tileBase = half * (N_TILES >> lsplit);
    const int nchunks  = (N_TILES >> lsplit) / CHUNK_T;   // 32 or 16

    // --- A fragments (built once). Lane supplies A[m=col][k=h*8+j].
    const float* xr = x_all + (size_t)(rowBase + col) * D_DIM + h * 8;
    const float4 xa = *(const float4*)xr;
    const float4 xb = *(const float4*)(xr + 4);
    const float xv[8] = {xa.x, xa.y, xa.z, xa.w, xb.x, xb.y, xb.z, xb.w};
    s16x8 a1, a2;
#pragma unroll
    for (int j = 0; j < 8; ++j) {
        const float a = -2.0f * xv[j];
        const unsigned short hh = f32_to_bf16_rne(a);
        a1[j] = (short)hh;
        a2[j] = (short)f32_to_bf16_rne(a - bf16_to_f32(hh));
    }
    // ones-A for the ysq-injection MFMA: A[m][k]=1 for k=0,1 (lanes<32), else 0.
    s16x8 aone;
#pragma unroll
    for (int j = 0; j < 8; ++j) aone[j] = 0;
    if (h == 0) { aone[0] = (short)0x3F80; aone[1] = (short)0x3F80; }

    f32x16 zero16;
#pragma unroll
    for (int r = 0; r < 16; ++r) zero16[r] = 0.f;

    // --- Staging: 12KB chunk = 1536 int2; 512 thr x 3 int2 (8B: conflict-free,
    // 2 lanes/bank is free). Prologue: chunk 0 -> buf0.
    const int2* gy = (const int2*)(yfrag + (size_t)tileBase * TILE_B);
    int2 ra = gy[tid];
    int2 rb = gy[512 + tid];
    int2 rc = gy[1024 + tid];
    {
        int2* s = (int2*)s_buf;
        s[tid] = ra; s[512 + tid] = rb; s[1024 + tid] = rc;
    }

    uint32_t best[16], second[16];
#pragma unroll
    for (int r = 0; r < 16; ++r) { best[r] = 0xFFFFFFFFu; second[r] = 0xFFFFFFFFu; }

    for (int ch = 0; ch < nchunks; ++ch) {
        // Prefetch next chunk into regs BEFORE the barrier (latency overlap).
        if (ch + 1 < nchunks) {
            const int base = (ch + 1) * 1536;
            ra = gy[base + tid];
            rb = gy[base + 512 + tid];
            rc = gy[base + 1024 + tid];
        }
        __syncthreads();   // buf[ch&1] writes (prev iter / prologue) visible

        const char* bb = s_buf + (ch & 1) * CHUNK_B + lane * 16;
#pragma unroll 1
        for (int t = 0; t < CHUNK_T; ++t) {
            const s16x8 byh = *(const s16x8*)(bb + t * TILE_B);          // conflict-free
            const s16x8 byl = *(const s16x8*)(bb + t * TILE_B + 1024);
            const s16x8 bys = *(const s16x8*)(bb + t * TILE_B + 2048);
            f32x16 acc = __builtin_amdgcn_mfma_f32_32x32x16_bf16(a1, byh, zero16, 0, 0, 0);
            acc = __builtin_amdgcn_mfma_f32_32x32x16_bf16(a2, byh, acc, 0, 0, 0);
            acc = __builtin_amdgcn_mfma_f32_32x32x16_bf16(a1, byl, acc, 0, 0, 0);
            acc = __builtin_amdgcn_mfma_f32_32x32x16_bf16(aone, bys, acc, 0, 0, 0);
            const uint32_t tcur = (uint32_t)(tileBase + ch * CHUNK_T + t);
#pragma unroll
            for (int r = 0; r < 16; ++r) {
                const uint32_t kb = (__float_as_uint(acc[r]) & 0xFFFFFF00u) | tcur;
                second[r] = med3_u32(best[r], kb, second[r]);  // = min(sec, max(best,kb))
                best[r]   = umin32(best[r], kb);
            }
        }
        // Write next chunk to the OTHER buffer (safe: its last readers were
        // fenced by this iteration's top barrier).
        if (ch + 1 < nchunks) {
            int2* s = (int2*)(s_buf + ((ch + 1) & 1) * CHUNK_B);
            s[tid] = ra; s[512 + tid] = rb; s[1024 + tid] = rc;
        }
    }

    // --- Reduce across the 32 columns. C/D: col=lane&31,
    // row=(r&3)+8*(r>>2)+4*h. Reuse s_buf: keys [wave*1024 + row*32 + col].
    __syncthreads();
    uint32_t* s_red = (uint32_t*)s_buf;            // 8*32*32 u32 = 32 KB
#pragma unroll
    for (int r = 0; r < 16; ++r) {
        const int row = (r & 3) + 8 * (r >> 2) + 4 * h;
        s_red[wave * 1024 + row * 32 + col] = best[r];
    }
    __syncthreads();

    uint32_t b1 = 0xFFFFFFFFu, b2 = 0xFFFFFFFFu;
    int cwin = 0;
    if (tid < 256) {
        const int w = tid >> 5, row = tid & 31;
#pragma unroll
        for (int c = 0; c < 32; ++c) {
            const uint32_t k = s_red[w * 1024 + row * 32 + c];
            cwin = (k < b1) ? c : cwin;         // strict <: earliest col on equal keys
            b2 = umin32(b2, umax32(b1, k));     // 2nd-min of bests
            b1 = umin32(b1, k);
        }
    }
    __syncthreads();
#pragma unroll
    for (int r = 0; r < 16; ++r) {
        const int row = (r & 3) + 8 * (r >> 2) + 4 * h;
        s_red[wave * 1024 + row * 32 + col] = second[r];
    }
    __syncthreads();

    if (tid < 256) {
        uint32_t smin = 0xFFFFFFFFu;
        const int w = tid >> 5, row = tid & 31;
#pragma unroll
        for (int c = 0; c < 32; ++c)
            smin = umin32(smin, s_red[w * 1024 + row * 32 + c]);
        const int m = mb * 256 + tid;           // = rowBase(w) + row
        const size_t idx = (size_t)half * M_ROWS + m;
        pbk[idx] = b1;
        psk[idx] = umin32(smin, b2);
        pn[idx]  = (b1 & 0xFFu) * 32 + (uint32_t)cwin;   // global n (tile is global)
    }
}

// ---------------------------------------------------------------------------
// Kernel 2b (merge): combine per-half partials exactly.
// best = min(bA,bB); second = min(min(sA,sB), max(bA,bB)).
// Halves have DISJOINT tile ranges -> equal keys impossible -> u32 order
// implements the earliest-n tie rule across halves (half0 tile < half1 tile).
// Then ambiguity test + color write / list append (same semantics as before).
// ---------------------------------------------------------------------------
__global__ __launch_bounds__(256) void merge_kernel(
    const uint32_t* __restrict__ pbk,
    const uint32_t* __restrict__ psk,
    const uint32_t* __restrict__ pn,
    const float* __restrict__ colors,
    float* __restrict__ out,
    int* __restrict__ cnt,
    int* __restrict__ list,
    int list_cap,
    int nsplit)
{
    const int m = blockIdx.x * 256 + threadIdx.x;
    if (m >= M_ROWS) return;

    uint32_t b = pbk[m];
    uint32_t s = psk[m];
    uint32_t n = pn[m];
    if (nsplit == 2) {
        const uint32_t b1 = pbk[M_ROWS + m];
        const uint32_t s1 = psk[M_ROWS + m];
        const uint32_t n1 = pn[M_ROWS + m];
        s = umin32(umin32(s, s1), umax32(b, b1));
        if (b1 < b) n = n1;        // b<=b1 keeps half0 (earliest n)
        b = umin32(b, b1);
    }
    const float sc1 = __uint_as_float(b & 0xFFFFFF00u);
    const float sc2 = __uint_as_float(s & 0xFFFFFF00u);

    bool amb = (sc2 - sc1 <= TIE_EPS);
    if (amb) {
        const int pos = atomicAdd(cnt, 1);
        if (pos < list_cap) list[pos] = m;
        else amb = false;                   // overflow: keep screened winner
    }
    if (!amb) {
        const float* cc = colors + (size_t)n * 3;
        float* o = out + (size_t)m * 3;
        o[0] = cc[0];
        o[1] = cc[1];
        o[2] = cc[2];
    }
}

// ---------------------------------------------------------------------------
// Kernel 3 (rescan): one wave per ambiguous row, fp64 exact (= f64 numpy ref),
// 8192 waves so latency is hidden by TLP; unroll-2 for ILP within a wave.
// ---------------------------------------------------------------------------
__global__ __launch_bounds__(256) void rescan_kernel(
    const float* __restrict__ x_all,
    const float* __restrict__ colors,
    const float* __restrict__ verts,
    const int* __restrict__ cnt,
    const int* __restrict__ list,
    int list_cap,
    float* __restrict__ out)
{
    const int wavesPerBlock = blockDim.x >> 6;
    const int wid  = blockIdx.x * wavesPerBlock + (threadIdx.x >> 6);
    const int lane = threadIdx.x & 63;
    const int nWaves = gridDim.x * wavesPerBlock;

    int ccount = *cnt;
    if (ccount > list_cap) ccount = list_cap;

    for (int rr = wid; rr < ccount; rr += nWaves) {
        const int m = list[rr];
        double bx[D_DIM];
#pragma unroll
        for (int d = 0; d < D_DIM; ++d)
            bx[d] = (double)x_all[(size_t)m * D_DIM + d];

        double best = INFINITY;
        int bi = 0x7fffffff;
#pragma unroll 2
        for (int n = lane; n < N_VERTS; n += 64) {
            const float* y = verts + (size_t)n * D_DIM;
            double dot = 0.0, ys = 0.0;
#pragma unroll
            for (int d = 0; d < D_DIM; ++d) {
                const double yd = (double)y[d];
                dot = fma(bx[d], yd, dot);
                ys  = fma(yd, yd, ys);
            }
            const double s = ys - 2.0 * dot;
            if (s < best || (s == best && n < bi)) { best = s; bi = n; }
        }
#pragma unroll
        for (int off = 32; off > 0; off >>= 1) {
            const double ob = __shfl_xor(best, off, 64);
            const int    oi = __shfl_xor(bi, off, 64);
            if (ob < best || (ob == best && oi < bi)) { best = ob; bi = oi; }
        }
        if (lane == 0) {
            const float* cc = colors + (size_t)bi * 3;
            float* o = out + (size_t)m * 3;
            o[0] = cc[0];
            o[1] = cc[1];
            o[2] = cc[2];
        }
    }
}

// ---------------------------------------------------------------------------
extern "C" void kernel_launch(void* const* d_in, const int* in_sizes, int n_in,
                              void* d_out, int out_size, void* d_ws, size_t ws_size,
                              hipStream_t stream) {
    const float* cse_embedding       = (const float*)d_in[0]; // (M,16)
    const float* verts_colors        = (const float*)d_in[1]; // (N,3)
    const float* verts_cse_embedding = (const float*)d_in[2]; // (N,16)
    float* out = (float*)d_out;                               // (M,3)

    char* ws = (char*)d_ws;
    char* yfrag = ws + WS_YFRAG_OFF;

    const size_t partB = (size_t)M_ROWS * 4;          // one partial array (u32[M])
    // split-2 layout: yfrag | pbk[2M] | psk[2M] | pn[2M] | cnt | list
    size_t need2 = WS_PART_OFF + 6 * partB + 64 + 64 * 1024;
    int nsplit = (ws_size >= need2) ? 2 : 1;
    const int lsplit = (nsplit == 2) ? 1 : 0;

    uint32_t* pbk = (uint32_t*)(ws + WS_PART_OFF);
    uint32_t* psk = (uint32_t*)(ws + WS_PART_OFF + (size_t)nsplit * partB);
    uint32_t* pn  = (uint32_t*)(ws + WS_PART_OFF + 2 * (size_t)nsplit * partB);
    size_t cntOff = WS_PART_OFF + 3 * (size_t)nsplit * partB;
    cntOff = (cntOff + 63) & ~(size_t)63;
    int* cnt  = (int*)(ws + cntOff);
    int* list = (int*)(ws + cntOff + 64);
    int list_cap = (ws_size > cntOff + 64)
                   ? (int)((ws_size - cntOff - 64) / sizeof(int)) : 0;
    if (list_cap > M_ROWS) list_cap = M_ROWS;

    pack_y_kernel<<<(N_TILES * 64) / 256, 256, 0, stream>>>(
        verts_cse_embedding, yfrag, cnt);

    mfma_screen_kernel<<<(M_ROWS / 256) * nsplit, 512, 0, stream>>>(
        cse_embedding, yfrag, pbk, psk, pn, lsplit);

    merge_kernel<<<M_ROWS / 256, 256, 0, stream>>>(
        pbk, psk, pn, verts_colors, out, cnt, list, list_cap, nsplit);

    rescan_kernel<<<2048, 256, 0, stream>>>(
        cse_embedding, verts_colors, verts_cse_embedding, cnt, list,
        list_cap, out);
}

// Round 7
// 166.202 us; speedup vs baseline: 2.1844x; 2.1844x over previous
//
#include <hip/hip_runtime.h>
#include <math.h>
#include <stdint.h>

// Problem: M=131072 rows, N=4000 verts (padded to 4096), D=16.
#define M_ROWS   131072
#define N_VERTS  4000
#define N_PAD    4096
#define D_DIM    16
#define N_TILES  (N_PAD / 32)          // 128 n-tiles of 32 verts
#define TILE_B   3072                  // per tile: yh 1KB | yl 1KB | ysf 1KB
#define CHUNK_T  8                     // tiles per LDS chunk
#define CHUNK_B  (CHUNK_T * TILE_B)    // 24576 B per chunk
#define N_CHUNKS (N_TILES / CHUNK_T)   // 16

// Scores are biased +128 so they are provably positive (score >= -||x||^2 and
// ||x||^2 < 128 for chi^2_16 data at astronomical confidence) -> positive-float
// bit pattern is monotone as u32 -> min_u32 does argmin via packed keys.
#define SCORE_BIAS 128.0f
// R7: key = (score_bits & ~0x7F) | tile -- tile 0..127 needs only SEVEN bits,
// so keep one more mantissa bit than before. Error budget: 7-bit truncation
// <= 3.9e-3 (score < 384 for near-best), dropped al*yl cross term <= 4.9e-4,
// ys bf16 hi+lo pair <= 7.3e-4, fp32 accum ~2e-4 -> delta <= 5.3e-3.
// TIE_EPS = 0.012 >= 2*delta. (R2-R6 shipped 0.03 with an 8-bit mask and
// passed absmax=0; this tightens the rescan set ~2.5x.)
#define TIE_EPS  0.012f
#define KEY_MASK 0xFFFFFF80u
#define TILE_MASK 0x7Fu

// d_ws layout (bytes):
//   [0      .. 393216)  yfrag : N_TILES x 3072 B, fragment-ordered 32x32 data
//   [393216 .. 393220)  cnt
//   [393280 .. ...   )  list  : ambiguous row indices
#define WS_YFRAG_OFF 0
#define WS_CNT_OFF   393216
#define WS_LIST_OFF  393280

typedef float f32x16 __attribute__((ext_vector_type(16)));
typedef short s16x8  __attribute__((ext_vector_type(8)));

__device__ __forceinline__ unsigned short f32_to_bf16_rne(float f) {
    unsigned int u = __float_as_uint(f);
    u = (u + 0x7fffu + ((u >> 16) & 1u)) >> 16;
    return (unsigned short)u;
}
__device__ __forceinline__ float bf16_to_f32(unsigned short h) {
    return __uint_as_float(((unsigned int)h) << 16);
}
__device__ __forceinline__ uint32_t umin32(uint32_t a, uint32_t b) { return a < b ? a : b; }
__device__ __forceinline__ uint32_t umax32(uint32_t a, uint32_t b) { return a > b ? a : b; }

// median(a,b,c) in one VALU op. Under the invariant a <= c this equals
// min(c, max(a, b)) -- the second-best update. LLVM can't derive this
// (only valid under the invariant), so force v_med3_u32 via asm.
// Case check (b=new key kb): kb<a -> a; a<=kb<=c -> kb; kb>c -> c.  All match.
// Invariant preserved: min(a,kb) <= min(c, max(a,kb)).  [verified R4, absmax=0]
__device__ __forceinline__ uint32_t med3_u32(uint32_t a, uint32_t b, uint32_t c) {
    uint32_t d;
    asm("v_med3_u32 %0, %1, %2, %3" : "=v"(d) : "v"(a), "v"(b), "v"(c));
    return d;
}

// ---------------------------------------------------------------------------
// Kernel 1: pack Y into 32x32-MFMA fragment order.
// B-operand layout for mfma_f32_32x32x16_bf16 (verified R1/R2, absmax=0):
// B[n = lane&31][k = (lane>>5)*8 + j].
// Per tile T (32 verts): yh frag (64 lanes x 16B), yl frag, ysf frag.
// ysf holds (bias+||y||^2) as a bf16 hi/lo pair in k-slots 0,1 (lanes<32),
// consumed by an extra MFMA against a "ones" A-fragment -> acc init via MFMA.
// One thread per (tile, lane) = 8192 threads.
// ---------------------------------------------------------------------------
__global__ void pack_y_kernel(const float* __restrict__ verts,
                              char* __restrict__ yfrag,
                              int* __restrict__ cnt) {
    const int tid = blockIdx.x * blockDim.x + threadIdx.x;   // 0..8191
    if (tid == 0) *cnt = 0;

    const int T   = tid >> 6;
    const int l   = tid & 63;
    const int col = l & 31;
    const int h   = l >> 5;
    const int n   = T * 32 + col;
    const int d0  = h * 8;

    float v[8];
    if (n < N_VERTS) {
        const float* y = verts + (size_t)n * D_DIM + d0;
#pragma unroll
        for (int j = 0; j < 8; ++j) v[j] = y[j];
    } else {
#pragma unroll
        for (int j = 0; j < 8; ++j) v[j] = 0.f;
    }
    s16x8 fh, fl;
#pragma unroll
    for (int j = 0; j < 8; ++j) {
        const unsigned short hh = f32_to_bf16_rne(v[j]);
        fh[j] = (short)hh;
        fl[j] = (short)f32_to_bf16_rne(v[j] - bf16_to_f32(hh));
    }
    char* tb = yfrag + (size_t)T * TILE_B + (size_t)l * 16;
    *(s16x8*)(tb)        = fh;
    *(s16x8*)(tb + 1024) = fl;

    // ysf: k-slots 0,1 (lanes < 32) hold bf16 hi/lo of bias+||y||^2.
    s16x8 fy;
#pragma unroll
    for (int j = 0; j < 8; ++j) fy[j] = 0;
    if (h == 0) {
        float ys;
        if (n < N_VERTS) {
            ys = SCORE_BIAS;
            const float* y = verts + (size_t)n * D_DIM;
#pragma unroll
            for (int d = 0; d < D_DIM; ++d) ys = fmaf(y[d], y[d], ys);
        } else {
            ys = 1e30f;   // pad cols never win
        }
        const unsigned short ysh = f32_to_bf16_rne(ys);
        fy[0] = (short)ysh;
        fy[1] = (short)f32_to_bf16_rne(ys - bf16_to_f32(ysh));
    }
    *(s16x8*)(tb + 2048) = fy;
}

// ---------------------------------------------------------------------------
// Kernel 2 (MFMA screen, 32x32x16): 512 thr = 8 waves, wave = 32 rows x all n.
// EXACT R4 structure (90.9 us verified): CHUNK_T=8, launch_bounds(512,4),
// reg-prefetch double-buffered LDS, one barrier per chunk.
// Per tile: acc = ah*yh + al*yh + ah*yl + ones*ysf (4 chained MFMAs).
// Key = (bits & ~0x7F) | tile -> min_u32 best, v_med3_u32 second.
//
// R6 post-mortem: forcing 8 waves/SIMD via launch_bounds(512,8) squeezed
// arch VGPRs to 32 -> best/second spilled (400 MB scratch, 240 us). Per-wave
// state caps this kernel at 4 waves/SIMD; do NOT raise the min-waves bound.
// R3 post-mortem: global_load_lds DMA staging FAILED correctness -- keep
// reg staging. R5: intra-wave 2-tile ILP REGRESSED (serial best[] RAW).
//
// R7 change: asm "+v" pin on acc after the MFMA chain. Theory: acc is
// AGPR-homed (VGPR_Count=48 < live state), so every key-pack pays a
// v_accvgpr_read_b32 (+16 VALU/tile) plus shuttling around med3's "v"
// constraints. gfx950's unified file allows MFMA D in VGPRs; the pin makes
// the allocator home acc there. If already VGPR: no-op.
// Spill tripwire: FETCH_SIZE must stay ~5.8 MB.
// ---------------------------------------------------------------------------
__global__ __launch_bounds__(512, 4) void mfma_screen_kernel(
    const float* __restrict__ x_all,    // (M,16)
    const float* __restrict__ colors,   // (N,3)
    const char* __restrict__ yfrag,     // N_TILES x 3072 B
    float* __restrict__ out,            // (M,3)
    int* __restrict__ cnt,
    int* __restrict__ list,
    int list_cap)
{
    __shared__ __align__(16) char s_buf[2 * CHUNK_B];   // 48 KB (reused for reduce)

    const int tid  = threadIdx.x;
    const int wave = tid >> 6;
    const int lane = tid & 63;
    const int col  = lane & 31;          // A row / B col / C-D col
    const int h    = lane >> 5;          // k-half select
    const int rowBase = blockIdx.x * 256 + wave * 32;

    // --- A fragments (built once). Lane supplies A[m=col][k=h*8+j].
    const float* xr = x_all + (size_t)(rowBase + col) * D_DIM + h * 8;
    const float4 xa = *(const float4*)xr;
    const float4 xb = *(const float4*)(xr + 4);
    const float xv[8] = {xa.x, xa.y, xa.z, xa.w, xb.x, xb.y, xb.z, xb.w};
    s16x8 a1, a2;
#pragma unroll
    for (int j = 0; j < 8; ++j) {
        const float a = -2.0f * xv[j];
        const unsigned short hh = f32_to_bf16_rne(a);
        a1[j] = (short)hh;
        a2[j] = (short)f32_to_bf16_rne(a - bf16_to_f32(hh));
    }
    // ones-A for the ysq-injection MFMA: A[m][k]=1 for k=0,1 (lanes<32), else 0.
    s16x8 aone;
#pragma unroll
    for (int j = 0; j < 8; ++j) aone[j] = 0;
    if (h == 0) { aone[0] = (short)0x3F80; aone[1] = (short)0x3F80; }

    f32x16 zero16;
#pragma unroll
    for (int r = 0; r < 16; ++r) zero16[r] = 0.f;

    // --- Prologue: chunk 0 -> buf0 (stride-16B per thread: conflict-free).
    const int4* gy = (const int4*)yfrag;
    int4 ra = gy[tid];
    int4 rb = gy[512 + tid];
    int4 rc = gy[1024 + tid];
    {
        int4* s = (int4*)s_buf;
        s[tid] = ra; s[512 + tid] = rb; s[1024 + tid] = rc;
    }

    uint32_t best[16], second[16];
#pragma unroll
    for (int r = 0; r < 16; ++r) { best[r] = 0xFFFFFFFFu; second[r] = 0xFFFFFFFFu; }

    for (int ch = 0; ch < N_CHUNKS; ++ch) {
        // Prefetch next chunk into regs BEFORE the barrier (latency overlap).
        if (ch + 1 < N_CHUNKS) {
            const int base = (ch + 1) * 1536;
            ra = gy[base + tid];
            rb = gy[base + 512 + tid];
            rc = gy[base + 1024 + tid];
        }
        __syncthreads();   // buf[ch&1] writes (prev iter / prologue) visible

        const char* bb = s_buf + (ch & 1) * CHUNK_B + lane * 16;
#pragma unroll 1
        for (int t = 0; t < CHUNK_T; ++t) {
            const s16x8 byh = *(const s16x8*)(bb + t * TILE_B);          // conflict-free
            const s16x8 byl = *(const s16x8*)(bb + t * TILE_B + 1024);
            const s16x8 bys = *(const s16x8*)(bb + t * TILE_B + 2048);
            f32x16 acc = __builtin_amdgcn_mfma_f32_32x32x16_bf16(a1, byh, zero16, 0, 0, 0);
            acc = __builtin_amdgcn_mfma_f32_32x32x16_bf16(a2, byh, acc, 0, 0, 0);
            acc = __builtin_amdgcn_mfma_f32_32x32x16_bf16(a1, byl, acc, 0, 0, 0);
            acc = __builtin_amdgcn_mfma_f32_32x32x16_bf16(aone, bys, acc, 0, 0, 0);
            // Pin acc to arch VGPRs so the key-pack below reads it directly
            // (no v_accvgpr_read shuttle). No-op if already VGPR-homed.
            asm volatile("" : "+v"(acc));
            const uint32_t tcur = (uint32_t)(ch * CHUNK_T + t);
#pragma unroll
            for (int r = 0; r < 16; ++r) {
                const uint32_t kb = (__float_as_uint(acc[r]) & KEY_MASK) | tcur;
                second[r] = med3_u32(best[r], kb, second[r]);  // = min(sec, max(best,kb))
                best[r]   = umin32(best[r], kb);
            }
        }
        // Write next chunk to the OTHER buffer (safe: its last readers were
        // fenced by this iteration's top barrier).
        if (ch + 1 < N_CHUNKS) {
            int4* s = (int4*)(s_buf + ((ch + 1) & 1) * CHUNK_B);
            s[tid] = ra; s[512 + tid] = rb; s[1024 + tid] = rc;
        }
    }

    // --- Reduce across the 32 columns. C/D: col=lane&31,
    // row=(r&3)+8*(r>>2)+4*h. Reuse s_buf: keys [wave*1024 + row*32 + col].
    __syncthreads();
    uint32_t* s_red = (uint32_t*)s_buf;            // 8*32*32 u32 = 32 KB
#pragma unroll
    for (int r = 0; r < 16; ++r) {
        const int row = (r & 3) + 8 * (r >> 2) + 4 * h;
        s_red[wave * 1024 + row * 32 + col] = best[r];
    }
    __syncthreads();

    uint32_t b1 = 0xFFFFFFFFu, b2 = 0xFFFFFFFFu;
    int cwin = 0;
    if (tid < 256) {
        const int w = tid >> 5, row = tid & 31;
#pragma unroll
        for (int c = 0; c < 32; ++c) {
            const uint32_t k = s_red[w * 1024 + row * 32 + c];
            cwin = (k < b1) ? c : cwin;         // strict <: earliest col on equal keys
            b2 = umin32(b2, umax32(b1, k));     // 2nd-min of bests
            b1 = umin32(b1, k);
        }
    }
    __syncthreads();
#pragma unroll
    for (int r = 0; r < 16; ++r) {
        const int row = (r & 3) + 8 * (r >> 2) + 4 * h;
        s_red[wave * 1024 + row * 32 + col] = second[r];
    }
    __syncthreads();

    if (tid < 256) {
        const int w = tid >> 5, row = tid & 31;
        uint32_t smin = 0xFFFFFFFFu;
#pragma unroll
        for (int c = 0; c < 32; ++c)
            smin = umin32(smin, s_red[w * 1024 + row * 32 + c]);
        const uint32_t secondAll = umin32(smin, b2);
        const float s1 = __uint_as_float(b1 & KEY_MASK);
        const float s2 = __uint_as_float(secondAll & KEY_MASK);
        const int n = (int)(b1 & TILE_MASK) * 32 + cwin;
        const int m = blockIdx.x * 256 + tid;   // = rowBase(w) + row

        bool amb = (s2 - s1 <= TIE_EPS);
        if (amb) {
            const int pos = atomicAdd(cnt, 1);
            if (pos < list_cap) list[pos] = m;
            else amb = false;                   // overflow: keep screened winner
        }
        if (!amb) {
            const float* cc2 = colors + (size_t)n * 3;
            float* o = out + (size_t)m * 3;
            o[0] = cc2[0];
            o[1] = cc2[1];
            o[2] = cc2[2];
        }
    }
}

// ---------------------------------------------------------------------------
// Kernel 3 (rescan): one wave per ambiguous row, fp64 exact (= f64 numpy ref),
// 8192 waves so latency is hidden by TLP; unroll-2 for ILP within a wave.
// ---------------------------------------------------------------------------
__global__ __launch_bounds__(256) void rescan_kernel(
    const float* __restrict__ x_all,
    const float* __restrict__ colors,
    const float* __restrict__ verts,
    const int* __restrict__ cnt,
    const int* __restrict__ list,
    int list_cap,
    float* __restrict__ out)
{
    const int wavesPerBlock = blockDim.x >> 6;
    const int wid  = blockIdx.x * wavesPerBlock + (threadIdx.x >> 6);
    const int lane = threadIdx.x & 63;
    const int nWaves = gridDim.x * wavesPerBlock;

    int ccount = *cnt;
    if (ccount > list_cap) ccount = list_cap;

    for (int rr = wid; rr < ccount; rr += nWaves) {
        const int m = list[rr];
        double bx[D_DIM];
#pragma unroll
        for (int d = 0; d < D_DIM; ++d)
            bx[d] = (double)x_all[(size_t)m * D_DIM + d];

        double best = INFINITY;
        int bi = 0x7fffffff;
#pragma unroll 2
        for (int n = lane; n < N_VERTS; n += 64) {
            const float* y = verts + (size_t)n * D_DIM;
            double dot = 0.0, ys = 0.0;
#pragma unroll
            for (int d = 0; d < D_DIM; ++d) {
                const double yd = (double)y[d];
                dot = fma(bx[d], yd, dot);
                ys  = fma(yd, yd, ys);
            }
            const double s = ys - 2.0 * dot;
            if (s < best || (s == best && n < bi)) { best = s; bi = n; }
        }
#pragma unroll
        for (int off = 32; off > 0; off >>= 1) {
            const double ob = __shfl_xor(best, off, 64);
            const int    oi = __shfl_xor(bi, off, 64);
            if (ob < best || (ob == best && oi < bi)) { best = ob; bi = oi; }
        }
        if (lane == 0) {
            const float* cc = colors + (size_t)bi * 3;
            float* o = out + (size_t)m * 3;
            o[0] = cc[0];
            o[1] = cc[1];
            o[2] = cc[2];
        }
    }
}

// ---------------------------------------------------------------------------
extern "C" void kernel_launch(void* const* d_in, const int* in_sizes, int n_in,
                              void* d_out, int out_size, void* d_ws, size_t ws_size,
                              hipStream_t stream) {
    const float* cse_embedding       = (const float*)d_in[0]; // (M,16)
    const float* verts_colors        = (const float*)d_in[1]; // (N,3)
    const float* verts_cse_embedding = (const float*)d_in[2]; // (N,16)
    float* out = (float*)d_out;                               // (M,3)

    char* ws = (char*)d_ws;
    char*  yfrag = ws + WS_YFRAG_OFF;
    int*   cnt   = (int*)(ws + WS_CNT_OFF);
    int*   list  = (int*)(ws + WS_LIST_OFF);
    int list_cap = (int)((ws_size > WS_LIST_OFF)
                         ? ((ws_size - WS_LIST_OFF) / sizeof(int)) : 0);
    if (list_cap > M_ROWS) list_cap = M_ROWS;

    pack_y_kernel<<<(N_TILES * 64) / 256, 256, 0, stream>>>(
        verts_cse_embedding, yfrag, cnt);

    mfma_screen_kernel<<<M_ROWS / 256, 512, 0, stream>>>(
        cse_embedding, verts_colors, yfrag, out, cnt, list, list_cap);

    rescan_kernel<<<2048, 256, 0, stream>>>(
        cse_embedding, verts_colors, verts_cse_embedding, cnt, list,
        list_cap, out);
}

// Round 8
// 164.008 us; speedup vs baseline: 2.2136x; 1.0134x over previous
//
#include <hip/hip_runtime.h>
#include <math.h>
#include <stdint.h>

// Problem: M=131072 rows, N=4000 verts (padded to 4096), D=16.
#define M_ROWS   131072
#define N_VERTS  4000
#define N_PAD    4096
#define D_DIM    16
#define N_TILES  (N_PAD / 32)          // 128 n-tiles of 32 verts
#define TILE_B   2048                  // per tile: yh 1KB | yl 1KB  (R8: ysf gone)
#define CHUNK_T  8                     // tiles per LDS chunk
#define CHUNK_B  (CHUNK_T * TILE_B)    // 16384 B per chunk
#define N_CHUNKS (N_TILES / CHUNK_T)   // 16

// Scores are biased +128 so they are provably positive (score >= -||x||^2 and
// ||x||^2 < 128 for chi^2_16 data at astronomical confidence) -> positive-float
// bit pattern is monotone as u32 -> min_u32 does argmin via packed keys.
#define SCORE_BIAS 128.0f
// key = (score_bits & ~0x7F) | tile (tile 0..127 in SEVEN bits).
// Error budget (R8): 7-bit truncation <= 3.9e-3, dropped al*yl cross term
// <= 4.9e-4, fp32 accum ~2e-4 (ysq now injected in EXACT fp32 -- the bf16
// hi/lo pair term is gone) -> delta <= 4.6e-3.  TIE_EPS = 0.012 >= 2*delta.
#define TIE_EPS  0.012f
#define KEY_MASK 0xFFFFFF80u
#define TILE_MASK 0x7Fu

// d_ws layout (bytes):
//   [0      .. 262144)  yfrag : N_TILES x 2048 B, fragment-ordered 32x32 data
//   [262144 .. 278528)  ysq   : N_PAD floats, bias+||y||^2 fp32 (pads 1e30)
//   [278528 .. 278532)  cnt
//   [278592 .. ...   )  list  : ambiguous row indices
#define WS_YFRAG_OFF 0
#define WS_YSQ_OFF   262144
#define WS_CNT_OFF   278528
#define WS_LIST_OFF  278592

typedef float f32x16 __attribute__((ext_vector_type(16)));
typedef short s16x8  __attribute__((ext_vector_type(8)));

__device__ __forceinline__ unsigned short f32_to_bf16_rne(float f) {
    unsigned int u = __float_as_uint(f);
    u = (u + 0x7fffu + ((u >> 16) & 1u)) >> 16;
    return (unsigned short)u;
}
__device__ __forceinline__ float bf16_to_f32(unsigned short h) {
    return __uint_as_float(((unsigned int)h) << 16);
}
__device__ __forceinline__ uint32_t umin32(uint32_t a, uint32_t b) { return a < b ? a : b; }
__device__ __forceinline__ uint32_t umax32(uint32_t a, uint32_t b) { return a > b ? a : b; }

// median(a,b,c) in one VALU op. Under the invariant a <= c this equals
// min(c, max(a, b)) -- the second-best update. LLVM can't derive this
// (only valid under the invariant), so force v_med3_u32 via asm.
// Case check (b=new key kb): kb<a -> a; a<=kb<=c -> kb; kb>c -> c.  All match.
// Invariant preserved: min(a,kb) <= min(c, max(a,kb)).  [verified R4, absmax=0]
__device__ __forceinline__ uint32_t med3_u32(uint32_t a, uint32_t b, uint32_t c) {
    uint32_t d;
    asm("v_med3_u32 %0, %1, %2, %3" : "=v"(d) : "v"(a), "v"(b), "v"(c));
    return d;
}

// ---------------------------------------------------------------------------
// Kernel 1: pack Y into 32x32-MFMA fragment order + fp32 biased ysq.
// B-operand layout for mfma_f32_32x32x16_bf16 (verified R1/R2, absmax=0):
// B[n = lane&31][k = (lane>>5)*8 + j].
// Per tile T (32 verts): yh frag (64 lanes x 16B) | yl frag.  (R8: the ysf
// fragment is GONE -- ysq is injected as the fp32 acc init in the screen,
// exploiting C/D col=lane&31 for all 16 regs.)
// One thread per (tile, lane) = 8192 threads.
// ---------------------------------------------------------------------------
__global__ void pack_y_kernel(const float* __restrict__ verts,
                              char* __restrict__ yfrag,
                              float* __restrict__ ysq,
                              int* __restrict__ cnt) {
    const int tid = blockIdx.x * blockDim.x + threadIdx.x;   // 0..8191
    if (tid == 0) *cnt = 0;

    const int T   = tid >> 6;
    const int l   = tid & 63;
    const int col = l & 31;
    const int h   = l >> 5;
    const int n   = T * 32 + col;
    const int d0  = h * 8;

    float v[8];
    if (n < N_VERTS) {
        const float* y = verts + (size_t)n * D_DIM + d0;
#pragma unroll
        for (int j = 0; j < 8; ++j) v[j] = y[j];
    } else {
#pragma unroll
        for (int j = 0; j < 8; ++j) v[j] = 0.f;
    }
    s16x8 fh, fl;
#pragma unroll
    for (int j = 0; j < 8; ++j) {
        const unsigned short hh = f32_to_bf16_rne(v[j]);
        fh[j] = (short)hh;
        fl[j] = (short)f32_to_bf16_rne(v[j] - bf16_to_f32(hh));
    }
    char* tb = yfrag + (size_t)T * TILE_B + (size_t)l * 16;
    *(s16x8*)(tb)        = fh;
    *(s16x8*)(tb + 1024) = fl;

    // ysq: fp32, bias baked in; pad columns get 1e30 so they never win.
    if (tid < N_PAD) {
        float ys;
        if (tid < N_VERTS) {
            ys = SCORE_BIAS;
            const float* y = verts + (size_t)tid * D_DIM;
#pragma unroll
            for (int d = 0; d < D_DIM; ++d) ys = fmaf(y[d], y[d], ys);
        } else {
            ys = 1e30f;
        }
        ysq[tid] = ys;
    }
}

// ---------------------------------------------------------------------------
// Kernel 2 (MFMA screen, 32x32x16): 512 thr = 8 waves, wave = 32 rows x all n.
// R4 loop structure (verified): CHUNK_T=8, launch_bounds(512,4), reg-prefetch
// double-buffered LDS, one barrier per chunk.
//
// R8: ysq via fp32 ACC INIT, not a 4th MFMA. C/D layout col=lane&31 for ALL
// 16 regs of a lane -> every acc value of a lane belongs to vertex
// n = tile*32 + col -> acc[r] = ysq_biased[n] splat + only 3 product MFMAs
// (ah*yh + al*yh + ah*yl). Removes: the serial 4th MFMA, the ysf third of
// LDS traffic (TILE_B 3072->2048), zero16 (16 live regs of zeros), aone,
// bys -- ~28 regs freed so best/second can be arch-VGPR-homed (R7 counter
// arithmetic: ~150 VALU/tile measured vs ~64 in source = accvgpr shuttles).
//
// R6 post-mortem: do NOT raise min-waves bound (VGPR squeeze -> spill).
// R3 post-mortem: global_load_lds DMA staging FAILED correctness -- keep
// reg staging. R5: intra-wave 2-tile ILP REGRESSED (serial best[] RAW).
// `#pragma unroll 1`: full unroll pipelines tiles -> spill (R1).
// Spill tripwire: FETCH_SIZE must stay ~<20 MB.
// ---------------------------------------------------------------------------
__global__ __launch_bounds__(512, 4) void mfma_screen_kernel(
    const float* __restrict__ x_all,    // (M,16)
    const float* __restrict__ colors,   // (N,3)
    const char* __restrict__ yfrag,     // N_TILES x 2048 B
    const float* __restrict__ ysqg,     // N_PAD fp32 (biased)
    float* __restrict__ out,            // (M,3)
    int* __restrict__ cnt,
    int* __restrict__ list,
    int list_cap)
{
    __shared__ __align__(16) char  s_buf[2 * CHUNK_B];   // 32 KB (reused for reduce)
    __shared__ __align__(16) float s_ysq[N_PAD];         // 16 KB

    const int tid  = threadIdx.x;
    const int wave = tid >> 6;
    const int lane = tid & 63;
    const int col  = lane & 31;          // A row / B col / C-D col
    const int h    = lane >> 5;          // k-half select
    const int rowBase = blockIdx.x * 256 + wave * 32;

    // --- A fragments (built once). Lane supplies A[m=col][k=h*8+j].
    const float* xr = x_all + (size_t)(rowBase + col) * D_DIM + h * 8;
    const float4 xa = *(const float4*)xr;
    const float4 xb = *(const float4*)(xr + 4);
    const float xv[8] = {xa.x, xa.y, xa.z, xa.w, xb.x, xb.y, xb.z, xb.w};
    s16x8 a1, a2;
#pragma unroll
    for (int j = 0; j < 8; ++j) {
        const float a = -2.0f * xv[j];
        const unsigned short hh = f32_to_bf16_rne(a);
        a1[j] = (short)hh;
        a2[j] = (short)f32_to_bf16_rne(a - bf16_to_f32(hh));
    }

    // --- Stage ysq once (1024 int4, 2 per thread). Fenced by first barrier.
    {
        const int4* g = (const int4*)ysqg;
        int4* s = (int4*)s_ysq;
        s[tid] = g[tid];
        s[tid + 512] = g[tid + 512];
    }
    // --- Prologue: chunk 0 -> buf0 (stride-16B per thread: conflict-free).
    const int4* gy = (const int4*)yfrag;
    int4 ra = gy[tid];
    int4 rb = gy[512 + tid];
    {
        int4* s = (int4*)s_buf;
        s[tid] = ra;
        s[512 + tid] = rb;
    }

    uint32_t best[16], second[16];
#pragma unroll
    for (int r = 0; r < 16; ++r) { best[r] = 0xFFFFFFFFu; second[r] = 0xFFFFFFFFu; }

    for (int ch = 0; ch < N_CHUNKS; ++ch) {
        // Prefetch next chunk into regs BEFORE the barrier (latency overlap).
        if (ch + 1 < N_CHUNKS) {
            ra = gy[(ch + 1) * 1024 + tid];
            rb = gy[(ch + 1) * 1024 + 512 + tid];
        }
        __syncthreads();   // buf[ch&1] writes (prev iter / prologue) visible

        const char*  bb    = s_buf + (ch & 1) * CHUNK_B + lane * 16;
        const float* ysrow = s_ysq + ch * CHUNK_T * 32 + col;
#pragma unroll 1
        for (int t = 0; t < CHUNK_T; ++t) {
            const s16x8 byh = *(const s16x8*)(bb + t * TILE_B);          // conflict-free
            const s16x8 byl = *(const s16x8*)(bb + t * TILE_B + 1024);
            const float ysn = ysrow[t * 32];   // per-lane scalar; lanes l/l+32 broadcast
            f32x16 acc;
#pragma unroll
            for (int r = 0; r < 16; ++r) acc[r] = ysn;
            acc = __builtin_amdgcn_mfma_f32_32x32x16_bf16(a1, byh, acc, 0, 0, 0);
            acc = __builtin_amdgcn_mfma_f32_32x32x16_bf16(a2, byh, acc, 0, 0, 0);
            acc = __builtin_amdgcn_mfma_f32_32x32x16_bf16(a1, byl, acc, 0, 0, 0);
            // Pin acc to arch VGPRs so the key-pack reads it directly
            // (no v_accvgpr_read shuttle).  [R7: verified win]
            asm volatile("" : "+v"(acc));
            const uint32_t tcur = (uint32_t)(ch * CHUNK_T + t);
#pragma unroll
            for (int r = 0; r < 16; ++r) {
                const uint32_t kb = (__float_as_uint(acc[r]) & KEY_MASK) | tcur;
                second[r] = med3_u32(best[r], kb, second[r]);  // = min(sec, max(best,kb))
                best[r]   = umin32(best[r], kb);
            }
        }
        // Write next chunk to the OTHER buffer (safe: its last readers were
        // fenced by this iteration's top barrier).
        if (ch + 1 < N_CHUNKS) {
            int4* s = (int4*)(s_buf + ((ch + 1) & 1) * CHUNK_B);
            s[tid] = ra;
            s[512 + tid] = rb;
        }
    }

    // --- Reduce across the 32 columns. C/D: col=lane&31,
    // row=(r&3)+8*(r>>2)+4*h. Reuse s_buf: keys [wave*1024 + row*32 + col].
    __syncthreads();
    uint32_t* s_red = (uint32_t*)s_buf;            // 8*32*32 u32 = 32 KB exactly
#pragma unroll
    for (int r = 0; r < 16; ++r) {
        const int row = (r & 3) + 8 * (r >> 2) + 4 * h;
        s_red[wave * 1024 + row * 32 + col] = best[r];
    }
    __syncthreads();

    uint32_t b1 = 0xFFFFFFFFu, b2 = 0xFFFFFFFFu;
    int cwin = 0;
    if (tid < 256) {
        const int w = tid >> 5, row = tid & 31;
#pragma unroll
        for (int c = 0; c < 32; ++c) {
            const uint32_t k = s_red[w * 1024 + row * 32 + c];
            cwin = (k < b1) ? c : cwin;         // strict <: earliest col on equal keys
            b2 = umin32(b2, umax32(b1, k));     // 2nd-min of bests
            b1 = umin32(b1, k);
        }
    }
    __syncthreads();
#pragma unroll
    for (int r = 0; r < 16; ++r) {
        const int row = (r & 3) + 8 * (r >> 2) + 4 * h;
        s_red[wave * 1024 + row * 32 + col] = second[r];
    }
    __syncthreads();

    if (tid < 256) {
        const int w = tid >> 5, row = tid & 31;
        uint32_t smin = 0xFFFFFFFFu;
#pragma unroll
        for (int c = 0; c < 32; ++c)
            smin = umin32(smin, s_red[w * 1024 + row * 32 + c]);
        const uint32_t secondAll = umin32(smin, b2);
        const float s1 = __uint_as_float(b1 & KEY_MASK);
        const float s2 = __uint_as_float(secondAll & KEY_MASK);
        const int n = (int)(b1 & TILE_MASK) * 32 + cwin;
        const int m = blockIdx.x * 256 + tid;   // = rowBase(w) + row

        bool amb = (s2 - s1 <= TIE_EPS);
        if (amb) {
            const int pos = atomicAdd(cnt, 1);
            if (pos < list_cap) list[pos] = m;
            else amb = false;                   // overflow: keep screened winner
        }
        if (!amb) {
            const float* cc2 = colors + (size_t)n * 3;
            float* o = out + (size_t)m * 3;
            o[0] = cc2[0];
            o[1] = cc2[1];
            o[2] = cc2[2];
        }
    }
}

// ---------------------------------------------------------------------------
// Kernel 3 (rescan): one wave per ambiguous row, fp64 exact (= f64 numpy ref),
// 8192 waves so latency is hidden by TLP; unroll-2 for ILP within a wave.
// ---------------------------------------------------------------------------
__global__ __launch_bounds__(256) void rescan_kernel(
    const float* __restrict__ x_all,
    const float* __restrict__ colors,
    const float* __restrict__ verts,
    const int* __restrict__ cnt,
    const int* __restrict__ list,
    int list_cap,
    float* __restrict__ out)
{
    const int wavesPerBlock = blockDim.x >> 6;
    const int wid  = blockIdx.x * wavesPerBlock + (threadIdx.x >> 6);
    const int lane = threadIdx.x & 63;
    const int nWaves = gridDim.x * wavesPerBlock;

    int ccount = *cnt;
    if (ccount > list_cap) ccount = list_cap;

    for (int rr = wid; rr < ccount; rr += nWaves) {
        const int m = list[rr];
        double bx[D_DIM];
#pragma unroll
        for (int d = 0; d < D_DIM; ++d)
            bx[d] = (double)x_all[(size_t)m * D_DIM + d];

        double best = INFINITY;
        int bi = 0x7fffffff;
#pragma unroll 2
        for (int n = lane; n < N_VERTS; n += 64) {
            const float* y = verts + (size_t)n * D_DIM;
            double dot = 0.0, ys = 0.0;
#pragma unroll
            for (int d = 0; d < D_DIM; ++d) {
                const double yd = (double)y[d];
                dot = fma(bx[d], yd, dot);
                ys  = fma(yd, yd, ys);
            }
            const double s = ys - 2.0 * dot;
            if (s < best || (s == best && n < bi)) { best = s; bi = n; }
        }
#pragma unroll
        for (int off = 32; off > 0; off >>= 1) {
            const double ob = __shfl_xor(best, off, 64);
            const int    oi = __shfl_xor(bi, off, 64);
            if (ob < best || (ob == best && oi < bi)) { best = ob; bi = oi; }
        }
        if (lane == 0) {
            const float* cc = colors + (size_t)bi * 3;
            float* o = out + (size_t)m * 3;
            o[0] = cc[0];
            o[1] = cc[1];
            o[2] = cc[2];
        }
    }
}

// ---------------------------------------------------------------------------
extern "C" void kernel_launch(void* const* d_in, const int* in_sizes, int n_in,
                              void* d_out, int out_size, void* d_ws, size_t ws_size,
                              hipStream_t stream) {
    const float* cse_embedding       = (const float*)d_in[0]; // (M,16)
    const float* verts_colors        = (const float*)d_in[1]; // (N,3)
    const float* verts_cse_embedding = (const float*)d_in[2]; // (N,16)
    float* out = (float*)d_out;                               // (M,3)

    char* ws = (char*)d_ws;
    char*  yfrag = ws + WS_YFRAG_OFF;
    float* ysq   = (float*)(ws + WS_YSQ_OFF);
    int*   cnt   = (int*)(ws + WS_CNT_OFF);
    int*   list  = (int*)(ws + WS_LIST_OFF);
    int list_cap = (int)((ws_size > WS_LIST_OFF)
                         ? ((ws_size - WS_LIST_OFF) / sizeof(int)) : 0);
    if (list_cap > M_ROWS) list_cap = M_ROWS;

    pack_y_kernel<<<(N_TILES * 64) / 256, 256, 0, stream>>>(
        verts_cse_embedding, yfrag, ysq, cnt);

    mfma_screen_kernel<<<M_ROWS / 256, 512, 0, stream>>>(
        cse_embedding, verts_colors, yfrag, ysq, out, cnt, list, list_cap);

    rescan_kernel<<<2048, 256, 0, stream>>>(
        cse_embedding, verts_colors, verts_cse_embedding, cnt, list,
        list_cap, out);
}